// Round 14
// baseline (123.056 us; speedup 1.0000x reference)
//
#include <hip/hip_runtime.h>
#include <cstdint>
#include <cstddef>

// ---- problem constants ----
#define SEQLEN 2048
#define NBATCH 2
#define NIND   256
#define NPOS   256
#define NCIN   512
#define NH     8
#define NDE    64
#define NDV    64
#define NREC   64

typedef __attribute__((ext_vector_type(8))) short s16x8;
typedef __attribute__((ext_vector_type(4))) float f32x4;

__device__ __forceinline__ unsigned short f2bf(float f) {
  union { float f; unsigned u; } v; v.f = f;
  unsigned r = v.u + 0x7fffu + ((v.u >> 16) & 1u);
  return (unsigned short)(r >> 16);
}

// async global->LDS, 16B per lane; LDS dest = wave-uniform base + lane*16
__device__ __forceinline__ void gload16(const unsigned short* g, unsigned short* l) {
  __builtin_amdgcn_global_load_lds(
      (const __attribute__((address_space(1))) unsigned int*)g,
      (__attribute__((address_space(3))) unsigned int*)l, 16, 0, 0);
}

// ---------------- prep: concat+pos transpose, all weight cvts, vsum zero ----------------
__global__ __launch_bounds__(256) void prep_k(const float* __restrict__ x,
                                              const float* __restrict__ Wq,
                                              const float* __restrict__ Wk,
                                              const float* __restrict__ Wv,
                                              const float* __restrict__ Wc,
                                              const float* __restrict__ Wres,
                                              const float* __restrict__ W1,
                                              const float* __restrict__ W2,
                                              unsigned short* __restrict__ xpt,
                                              unsigned short* __restrict__ wqb,
                                              unsigned short* __restrict__ wkb,
                                              unsigned short* __restrict__ wvb,
                                              unsigned short* __restrict__ wcb,
                                              unsigned short* __restrict__ wresb,
                                              unsigned short* __restrict__ w1b,
                                              unsigned short* __restrict__ w2b,
                                              float* __restrict__ vsum) {
  __shared__ float tile[64][65];
  int blk = blockIdx.x;
  int t = threadIdx.x;
  if (blk < 512) {
    int b = blk >> 8, c0 = ((blk >> 5) & 7) * 64, l0 = (blk & 31) * 64;
    if (c0 < NIND) {
      const float* src = x + ((size_t)b * NIND + c0) * SEQLEN;
      int ll = t & 63, cq = t >> 6;
#pragma unroll
      for (int i = 0; i < 16; ++i) {
        int cl = cq * 16 + i;
        tile[cl][ll] = src[(size_t)cl * SEQLEN + l0 + ll];
      }
      __syncthreads();
      int cl2 = t & 63, lq = t >> 6;
      unsigned short* dst = xpt + ((size_t)b * SEQLEN + l0) * NCIN + c0;
#pragma unroll
      for (int i = 0; i < 16; ++i) {
        int l = lq * 16 + i;
        dst[(size_t)l * NCIN + cl2] = f2bf(tile[cl2][l]);
      }
    } else {
      if (b == 1) return;              // pos is batch-independent; b==0 block writes both
      int c = c0 + (t & 63);
      int j = c - NIND;
      int i = (j < NPOS / 2) ? j : j - NPOS / 2;
      const double base = (double)1.2f;
      double p = 1.0;
      for (int tt = 0; tt <= i; ++tt) p *= base;
      float w = 0.8f + (float)p;
      float swl = (float)SEQLEN / w;
      const float two_pi = (float)(2.0 * 3.14159265358979323846);
      int wv = t >> 6;
      unsigned short* dst0 = xpt;
      unsigned short* dst1 = xpt + (size_t)SEQLEN * NCIN;
#pragma unroll
      for (int it = 0; it < 16; ++it) {
        int l = l0 + 16 * wv + it;
        float arg = (two_pi * (float)l) / swl;
        unsigned short val = f2bf((j < NPOS / 2) ? sinf(arg) : cosf(arg));
        dst0[(size_t)l * NCIN + c] = val;
        dst1[(size_t)l * NCIN + c] = val;
      }
    }
  } else if (blk == 1360) {
    ((float4*)vsum)[t] = make_float4(0.f, 0.f, 0.f, 0.f);
  } else {
    const float* in;
    unsigned short* out;
    int idx4;
    if (blk < 1280) {
      int i = (blk - 512) * 256 + t;
      int which = i >> 16;
      idx4 = i & 65535;
      in = (which == 0) ? Wq : ((which == 1) ? Wk : Wv);
      out = (which == 0) ? wqb : ((which == 1) ? wkb : wvb);
    } else if (blk < 1312) { in = Wc;   out = wcb;   idx4 = (blk - 1280) * 256 + t; }
    else if (blk < 1328)   { in = Wres; out = wresb; idx4 = (blk - 1312) * 256 + t; }
    else if (blk < 1344)   { in = W1;   out = w1b;   idx4 = (blk - 1328) * 256 + t; }
    else                   { in = W2;   out = w2b;   idx4 = (blk - 1344) * 256 + t; }
    float4 v = ((const float4*)in)[idx4];
    ((ushort4*)out)[idx4] = make_ushort4(f2bf(v.x), f2bf(v.y), f2bf(v.z), f2bf(v.w));
  }
}

// ---------------- fused QKV MFMA GEMM: 64x128, BK=64, 2-deep counted-vmcnt pipeline ----------------
__global__ __launch_bounds__(256) void qkv_gemm_k(const unsigned short* __restrict__ Wqb,
                                                  const unsigned short* __restrict__ Wkb,
                                                  const unsigned short* __restrict__ Wvb,
                                                  const unsigned short* __restrict__ xpt,
                                                  unsigned short* __restrict__ qt,
                                                  unsigned short* __restrict__ kt,
                                                  unsigned short* __restrict__ vb,
                                                  float* __restrict__ vsum) {
  __shared__ alignas(16) unsigned short lds[24576];   // 2 x (A 64x64 | B 128x64)

  int bz = blockIdx.z;
  int y = blockIdx.y;
  int ysel = y >> 3;
  int m0 = (y & 7) * 64;
  int n0 = blockIdx.x * 128;
  const unsigned short* W = (ysel == 0) ? Wqb : ((ysel == 1) ? Wkb : Wvb);
  const unsigned short* Bg = xpt + (size_t)bz * SEQLEN * NCIN;

  int t = threadIdx.x;
  int w = t >> 6, lane = t & 63, lr = lane & 15, hi = lane >> 4;
  int wm = w >> 1, wn = w & 1;

  int sr = lane >> 3;
  int scs = ((lane & 7) ^ sr) * 8;   // shorts, source pre-swizzled by row
  const unsigned short* gA0 = W  + (size_t)(m0 + 16 * w + sr) * 512 + scs;
  const unsigned short* gB0 = Bg + (size_t)(n0 + 32 * w + sr) * 512 + scs;

  int swz = (lr & 7) << 3;           // read-side XOR (shorts)

  f32x4 acc[2][4];
#pragma unroll
  for (int i = 0; i < 2; ++i)
#pragma unroll
    for (int j = 0; j < 4; ++j) acc[i][j] = (f32x4){0.f, 0.f, 0.f, 0.f};

  auto stage = [&](int buf, int k0) {
    unsigned short* Ad = lds + buf * 12288 + (16 * w) * 64;
    unsigned short* Bd = lds + buf * 12288 + 4096 + (32 * w) * 64;
    gload16(gA0 + k0,            Ad);
    gload16(gA0 + k0 + 8 * 512,  Ad + 8 * 64);
    gload16(gB0 + k0,            Bd);
    gload16(gB0 + k0 + 8 * 512,  Bd + 8 * 64);
    gload16(gB0 + k0 + 16 * 512, Bd + 16 * 64);
    gload16(gB0 + k0 + 24 * 512, Bd + 24 * 64);
  };
  auto compute = [&](int buf) {
    const unsigned short* Ar = lds + buf * 12288;
    const unsigned short* Br = Ar + 4096;
#pragma unroll
    for (int ks = 0; ks < 2; ++ks) {
      s16x8 af[2], bfv[4];
#pragma unroll
      for (int mt = 0; mt < 2; ++mt)
        af[mt] = *(const s16x8*)&Ar[(32 * wm + 16 * mt + lr) * 64 + ((32 * ks + 8 * hi) ^ swz)];
#pragma unroll
      for (int nt = 0; nt < 4; ++nt)
        bfv[nt] = *(const s16x8*)&Br[(64 * wn + 16 * nt + lr) * 64 + ((32 * ks + 8 * hi) ^ swz)];
#pragma unroll
      for (int mt = 0; mt < 2; ++mt)
#pragma unroll
        for (int nt = 0; nt < 4; ++nt)
          acc[mt][nt] = __builtin_amdgcn_mfma_f32_16x16x32_bf16(af[mt], bfv[nt], acc[mt][nt], 0, 0, 0);
    }
  };

  stage(0, 0);
  stage(1, 64);
#pragma unroll
  for (int it = 0; it < 8; ++it) {
    if (it < 7) {
      asm volatile("s_waitcnt vmcnt(6)" ::: "memory");
    } else {
      asm volatile("s_waitcnt vmcnt(0)" ::: "memory");
    }
    __builtin_amdgcn_s_barrier();
    compute(it & 1);
    __builtin_amdgcn_s_barrier();
    if (it < 6) stage(it & 1, (it + 2) * 64);
  }
  __syncthreads();

  if (ysel == 2) {
#pragma unroll
    for (int mt = 0; mt < 2; ++mt)
#pragma unroll
      for (int reg = 0; reg < 4; ++reg) {
        float p = acc[mt][0][reg] + acc[mt][1][reg] + acc[mt][2][reg] + acc[mt][3][reg];
        p += __shfl_xor(p, 1, 64);
        p += __shfl_xor(p, 2, 64);
        p += __shfl_xor(p, 4, 64);
        p += __shfl_xor(p, 8, 64);
        if (lr == 0)
          atomicAdd(&vsum[bz * 512 + m0 + 32 * wm + 16 * mt + 4 * hi + reg], p);
      }
  }

  if (ysel < 2) {
    unsigned short* Cl = lds;
#pragma unroll
    for (int mt = 0; mt < 2; ++mt)
#pragma unroll
      for (int nt = 0; nt < 4; ++nt) {
        int lloc = 64 * wn + 16 * nt + lr;
        int d0 = 32 * wm + 16 * mt + 4 * hi;
        *(ushort4*)&Cl[lloc * 68 + d0] = make_ushort4(f2bf(acc[mt][nt][0]), f2bf(acc[mt][nt][1]),
                                                      f2bf(acc[mt][nt][2]), f2bf(acc[mt][nt][3]));
      }
    __syncthreads();
    int h = m0 >> 6;
    unsigned short* Cb = ((ysel == 0) ? qt : kt) + ((size_t)(bz * NH + h) * SEQLEN + n0) * 64;
    int rr = t >> 1, cc = (t & 1) * 32;
#pragma unroll
    for (int j = 0; j < 4; ++j)
      *(int4*)&Cb[(size_t)rr * 64 + cc + 8 * j] = *(const int4*)&Cl[rr * 68 + cc + 8 * j];
  } else {
    unsigned short* Cl2 = lds;
#pragma unroll
    for (int mt = 0; mt < 2; ++mt)
#pragma unroll
      for (int nt = 0; nt < 4; ++nt) {
        int lloc = 64 * wn + 16 * nt + lr;
#pragma unroll
        for (int reg = 0; reg < 4; ++reg)
          Cl2[(32 * wm + 16 * mt + 4 * hi + reg) * 132 + lloc] = f2bf(acc[mt][nt][reg]);
      }
    __syncthreads();
    int dd = t >> 2, cc = (t & 3) * 32;
    unsigned short* Vb = vb + ((size_t)(bz * 512 + m0 + dd)) * SEQLEN + n0;
#pragma unroll
    for (int j = 0; j < 4; ++j)
      *(int4*)&Vb[cc + 8 * j] = *(const int4*)&Cl2[dd * 132 + cc + 8 * j];
  }
}

// ---------------- fused attn+tail: one wave per (b, 16-row tile), all 8 heads in LDS ----------------
// Per head: QK^T (144-window) -> softmax -> PV into attn_loc[16][520] LDS.
// Then tail (Wc/Wres + LN1 -> gelu(W1) -> W2 + LN2) reads attn rows from LDS.
#define ALP 520   // attn_loc pitch in shorts: 4-bank row stride -> 2-way (free)
__global__ __launch_bounds__(64) void attn_tail_k(
    const unsigned short* __restrict__ qt, const unsigned short* __restrict__ kt,
    const unsigned short* __restrict__ vb, const float* __restrict__ vsum,
    const unsigned short* __restrict__ wcb, const unsigned short* __restrict__ wresb,
    const unsigned short* __restrict__ w1b, const unsigned short* __restrict__ w2b,
    const unsigned short* __restrict__ xpt,
    const float* __restrict__ g1v, const float* __restrict__ b1v,
    const float* __restrict__ g2v, const float* __restrict__ b2v,
    float* __restrict__ outp) {
  __shared__ alignas(16) unsigned short attn_loc[16][ALP];  // 16640 B
  __shared__ alignas(16) unsigned short Ps[16][168];        // 5376 B
  __shared__ float rowcoef[16];
  __shared__ alignas(16) unsigned short pw[16][72];         // 2304 B
  __shared__ alignas(16) unsigned short hw[16][264];        // 8448 B
  __shared__ float gs1[64], bs1[64], gs2[64], bs2[64];

  int b = blockIdx.y;
  int l0 = blockIdx.x * 16;
  int t = threadIdx.x;                 // one wave
  int lr = t & 15, hi = t >> 4;

  gs1[t] = g1v[t]; bs1[t] = b1v[t]; gs2[t] = g2v[t]; bs2[t] = b2v[t];

  // ================= attention: loop over 8 heads =================
  for (int h = 0; h < NH; ++h) {
    const unsigned short* Qb = qt + (size_t)(b * NH + h) * SEQLEN * 64;
    const unsigned short* Kb = kt + (size_t)(b * NH + h) * SEQLEN * 64;
    const unsigned short* Vp = vb + (size_t)(b * 512 + h * 64) * SEQLEN;
    int vsbase = b * 512 + h * 64;

    s16x8 a0 = *(const s16x8*)(Qb + ((size_t)(l0 + lr)) * 64 + 8 * hi);
    s16x8 a1 = *(const s16x8*)(Qb + ((size_t)(l0 + lr)) * 64 + 32 + 8 * hi);

    f32x4 sc[9];
#pragma unroll
    for (int ct = 0; ct < 9; ++ct) {
      int m = l0 - 64 + 16 * ct + lr;
      const unsigned short* kp = Kb + (ptrdiff_t)m * 64;
      s16x8 b0 = *(const s16x8*)(kp + 8 * hi);
      s16x8 b1 = *(const s16x8*)(kp + 32 + 8 * hi);
      f32x4 acc = {0.f, 0.f, 0.f, 0.f};
      acc = __builtin_amdgcn_mfma_f32_16x16x32_bf16(a0, b0, acc, 0, 0, 0);
      acc = __builtin_amdgcn_mfma_f32_16x16x32_bf16(a1, b1, acc, 0, 0, 0);
      sc[ct] = acc;
    }

    float rcv[4];
#pragma unroll
    for (int i = 0; i < 4; ++i) {
      int r = 4 * hi + i;
      int l = l0 + r;
      float mx = 0.0f;
      float sv[9];
#pragma unroll
      for (int ct = 0; ct < 9; ++ct) {
        int c = 16 * ct + lr;
        int m = l0 - 64 + c;
        bool ib = (c >= r) && (c <= r + 128) && (m >= 0) && (m < SEQLEN);
        float s = sc[ct][i] * 0.125f;
        sv[ct] = ib ? s : -1e30f;
        mx = ib ? fmaxf(mx, s) : mx;
      }
      mx = fmaxf(mx, __shfl_xor(mx, 1, 64));
      mx = fmaxf(mx, __shfl_xor(mx, 2, 64));
      mx = fmaxf(mx, __shfl_xor(mx, 4, 64));
      mx = fmaxf(mx, __shfl_xor(mx, 8, 64));
      float e0 = expf(-mx);
      float zs = 0.f;
#pragma unroll
      for (int ct = 0; ct < 9; ++ct) {
        float e = (sv[ct] > -1e29f) ? expf(sv[ct] - mx) : 0.0f;
        sv[ct] = e;
        zs += e;
      }
      zs += __shfl_xor(zs, 1, 64);
      zs += __shfl_xor(zs, 2, 64);
      zs += __shfl_xor(zs, 4, 64);
      zs += __shfl_xor(zs, 8, 64);
      int lo = l - NREC; if (lo < 0) lo = 0;
      int hi2 = l + NREC; if (hi2 > SEQLEN - 1) hi2 = SEQLEN - 1;
      float inv = 1.0f / (zs + (float)(SEQLEN - (hi2 - lo + 1)) * e0);
      rcv[i] = e0 * inv;
#pragma unroll
      for (int ct = 0; ct < 9; ++ct)
        sc[ct][i] = (sv[ct] > 0.0f) ? (sv[ct] - e0) * inv : 0.0f;
    }

#pragma unroll
    for (int i = 0; i < 4; ++i) {
      int r = 4 * hi + i;
#pragma unroll
      for (int ct = 0; ct < 9; ++ct)
        Ps[r][16 * ct + lr] = f2bf(sc[ct][i]);
    }
    for (int z = t; z < 16 * 24; z += 64) Ps[z / 24][144 + z % 24] = 0;
    if (lr == 0) {
#pragma unroll
      for (int i = 0; i < 4; ++i) rowcoef[4 * hi + i] = rcv[i];
    }
    __syncthreads();

    float rcf = rowcoef[lr];
#pragma unroll
    for (int vt = 0; vt < 4; ++vt) {
      f32x4 acc = {0.f, 0.f, 0.f, 0.f};
#pragma unroll
      for (int ks = 0; ks < 5; ++ks) {
        int m8 = l0 - 64 + 32 * ks + 8 * hi;
        s16x8 av = *(const s16x8*)(Vp + (ptrdiff_t)(16 * vt + lr) * SEQLEN + m8);
        s16x8 bfr = *(const s16x8*)&Ps[lr][32 * ks + 8 * hi];
        acc = __builtin_amdgcn_mfma_f32_16x16x32_bf16(av, bfr, acc, 0, 0, 0);
      }
      float vsv[4];
#pragma unroll
      for (int reg = 0; reg < 4; ++reg) vsv[reg] = vsum[vsbase + 16 * vt + 4 * hi + reg];
      ushort4 o = make_ushort4(f2bf(acc[0] + rcf * vsv[0]), f2bf(acc[1] + rcf * vsv[1]),
                               f2bf(acc[2] + rcf * vsv[2]), f2bf(acc[3] + rcf * vsv[3]));
      *(ushort4*)&attn_loc[lr][h * 64 + 16 * vt + 4 * hi] = o;
    }
    __syncthreads();   // Ps reuse next head; attn_loc writes ordered
  }

  // ================= tail (reads attn rows from LDS) =================
  const unsigned short* xrow = xpt + ((size_t)b * SEQLEN + l0 + lr) * 512;

  f32x4 acc[4];
#pragma unroll
  for (int i = 0; i < 4; ++i) acc[i] = (f32x4){0.f, 0.f, 0.f, 0.f};
#pragma unroll
  for (int ks = 0; ks < 16; ++ks) {
    s16x8 bf = *(const s16x8*)&attn_loc[lr][32 * ks + 8 * hi];
#pragma unroll
    for (int mt = 0; mt < 4; ++mt) {
      s16x8 af = *(const s16x8*)(wcb + (size_t)(16 * mt + lr) * 512 + 32 * ks + 8 * hi);
      acc[mt] = __builtin_amdgcn_mfma_f32_16x16x32_bf16(af, bf, acc[mt], 0, 0, 0);
    }
  }
#pragma unroll
  for (int ks = 0; ks < 8; ++ks) {
    s16x8 bf = *(const s16x8*)(xrow + 32 * ks + 8 * hi);
#pragma unroll
    for (int mt = 0; mt < 4; ++mt) {
      s16x8 af = *(const s16x8*)(wresb + (size_t)(16 * mt + lr) * 256 + 32 * ks + 8 * hi);
      acc[mt] = __builtin_amdgcn_mfma_f32_16x16x32_bf16(af, bf, acc[mt], 0, 0, 0);
    }
  }
  float resid[4][4];
  {
    float sum = 0.f, sq = 0.f;
#pragma unroll
    for (int mt = 0; mt < 4; ++mt)
#pragma unroll
      for (int reg = 0; reg < 4; ++reg) { float v = acc[mt][reg]; sum += v; sq += v * v; }
    sum += __shfl_xor(sum, 16, 64); sq += __shfl_xor(sq, 16, 64);
    sum += __shfl_xor(sum, 32, 64); sq += __shfl_xor(sq, 32, 64);
    float mu = sum * (1.0f / 64.0f);
    float var = sq * (1.0f / 64.0f) - mu * mu;
    float rstd = rsqrtf(var + 1e-5f);
#pragma unroll
    for (int mt = 0; mt < 4; ++mt) {
      float o[4];
#pragma unroll
      for (int reg = 0; reg < 4; ++reg) {
        int m = 16 * mt + 4 * hi + reg;
        o[reg] = (acc[mt][reg] - mu) * rstd * gs1[m] + bs1[m];
        resid[mt][reg] = o[reg];
      }
      *(ushort4*)&pw[lr][16 * mt + 4 * hi] =
          make_ushort4(f2bf(o[0]), f2bf(o[1]), f2bf(o[2]), f2bf(o[3]));
    }
  }
  __syncthreads();

  {
    s16x8 bf0 = *(const s16x8*)&pw[lr][8 * hi];
    s16x8 bf1 = *(const s16x8*)&pw[lr][32 + 8 * hi];
#pragma unroll
    for (int mt = 0; mt < 16; ++mt) {
      s16x8 a0 = *(const s16x8*)(w1b + (size_t)(16 * mt + lr) * 64 + 8 * hi);
      s16x8 a1 = *(const s16x8*)(w1b + (size_t)(16 * mt + lr) * 64 + 32 + 8 * hi);
      f32x4 a2 = {0.f, 0.f, 0.f, 0.f};
      a2 = __builtin_amdgcn_mfma_f32_16x16x32_bf16(a0, bf0, a2, 0, 0, 0);
      a2 = __builtin_amdgcn_mfma_f32_16x16x32_bf16(a1, bf1, a2, 0, 0, 0);
      float v0 = a2[0], v1 = a2[1], v2 = a2[2], v3 = a2[3];
      v0 = 0.5f * v0 * (1.0f + erff(v0 * 0.70710678118654752440f));
      v1 = 0.5f * v1 * (1.0f + erff(v1 * 0.70710678118654752440f));
      v2 = 0.5f * v2 * (1.0f + erff(v2 * 0.70710678118654752440f));
      v3 = 0.5f * v3 * (1.0f + erff(v3 * 0.70710678118654752440f));
      *(ushort4*)&hw[lr][16 * mt + 4 * hi] = make_ushort4(f2bf(v0), f2bf(v1), f2bf(v2), f2bf(v3));
    }
  }
  __syncthreads();

  f32x4 acc3[4];
#pragma unroll
  for (int i = 0; i < 4; ++i) acc3[i] = (f32x4){0.f, 0.f, 0.f, 0.f};
#pragma unroll
  for (int ks = 0; ks < 8; ++ks) {
    s16x8 bf = *(const s16x8*)&hw[lr][32 * ks + 8 * hi];
#pragma unroll
    for (int mt = 0; mt < 4; ++mt) {
      s16x8 af = *(const s16x8*)(w2b + (size_t)(16 * mt + lr) * 256 + 32 * ks + 8 * hi);
      acc3[mt] = __builtin_amdgcn_mfma_f32_16x16x32_bf16(af, bf, acc3[mt], 0, 0, 0);
    }
  }
#pragma unroll
  for (int mt = 0; mt < 4; ++mt)
#pragma unroll
    for (int reg = 0; reg < 4; ++reg) acc3[mt][reg] += resid[mt][reg];
  float sum = 0.f, sq = 0.f;
#pragma unroll
  for (int mt = 0; mt < 4; ++mt)
#pragma unroll
    for (int reg = 0; reg < 4; ++reg) { float v = acc3[mt][reg]; sum += v; sq += v * v; }
  sum += __shfl_xor(sum, 16, 64); sq += __shfl_xor(sq, 16, 64);
  sum += __shfl_xor(sum, 32, 64); sq += __shfl_xor(sq, 32, 64);
  float mu = sum * (1.0f / 64.0f);
  float var = sq * (1.0f / 64.0f) - mu * mu;
  float rstd = rsqrtf(var + 1e-5f);
  float* ob = outp + (size_t)b * 64 * SEQLEN;
  int l = l0 + lr;
#pragma unroll
  for (int mt = 0; mt < 4; ++mt)
#pragma unroll
    for (int reg = 0; reg < 4; ++reg) {
      int m = 16 * mt + 4 * hi + reg;
      ob[(size_t)m * SEQLEN + l] = (acc3[mt][reg] - mu) * rstd * gs2[m] + bs2[m];
    }
}

extern "C" void kernel_launch(void* const* d_in, const int* in_sizes, int n_in,
                              void* d_out, int out_size, void* d_ws, size_t ws_size,
                              hipStream_t stream) {
  const float* x    = (const float*)d_in[0];
  const float* Wq   = (const float*)d_in[1];
  const float* Wk   = (const float*)d_in[2];
  const float* Wv   = (const float*)d_in[3];
  const float* Wres = (const float*)d_in[4];
  const float* Wc   = (const float*)d_in[5];
  const float* ln1g = (const float*)d_in[6];
  const float* ln1b = (const float*)d_in[7];
  const float* W1   = (const float*)d_in[8];
  const float* W2   = (const float*)d_in[9];
  const float* ln2g = (const float*)d_in[10];
  const float* ln2b = (const float*)d_in[11];

  char* base = (char*)d_ws;
  unsigned short* xpt   = (unsigned short*)base; base += (size_t)2097152 * 2;
  unsigned short* wqb   = (unsigned short*)base; base += (size_t)262144 * 2;
  unsigned short* wkb   = (unsigned short*)base; base += (size_t)262144 * 2;
  unsigned short* wvb   = (unsigned short*)base; base += (size_t)262144 * 2;
  unsigned short* wcb   = (unsigned short*)base; base += (size_t)32768 * 2;
  unsigned short* wresb = (unsigned short*)base; base += (size_t)16384 * 2;
  unsigned short* w1b   = (unsigned short*)base; base += (size_t)16384 * 2;
  unsigned short* w2b   = (unsigned short*)base; base += (size_t)16384 * 2;
  unsigned short* qt    = (unsigned short*)base; base += (size_t)2097152 * 2;
  unsigned short* kt    = (unsigned short*)base; base += (size_t)2097152 * 2;
  unsigned short* vbb   = (unsigned short*)base; base += (size_t)2097152 * 2;
  float* vsum           = (float*)base;          base += (size_t)1024 * 4;
  float* outp = (float*)d_out;

  prep_k<<<1361, 256, 0, stream>>>(x, Wq, Wk, Wv, Wc, Wres, W1, W2,
                                   xpt, wqb, wkb, wvb, wcb, wresb, w1b, w2b, vsum);
  qkv_gemm_k<<<dim3(16, 24, NBATCH), 256, 0, stream>>>(wqb, wkb, wvb, xpt, qt, kt, vbb, vsum);
  attn_tail_k<<<dim3(128, NBATCH), 64, 0, stream>>>(qt, kt, vbb, vsum,
                                                    wcb, wresb, w1b, w2b, xpt,
                                                    ln1g, ln1b, ln2g, ln2b, outp);
}

// Round 15
// 70.523 us; speedup vs baseline: 1.7449x; 1.7449x over previous
//
#include <hip/hip_runtime.h>
#include <cstdint>
#include <cstddef>

// ---- problem constants ----
#define SEQLEN 2048
#define NBATCH 2
#define NIND   256
#define NPOS   256
#define NCIN   512
#define NH     8
#define NDE    64
#define NDV    64
#define NREC   64

typedef __attribute__((ext_vector_type(8))) short s16x8;
typedef __attribute__((ext_vector_type(4))) float f32x4;

__device__ __forceinline__ unsigned short f2bf(float f) {
  union { float f; unsigned u; } v; v.f = f;
  unsigned r = v.u + 0x7fffu + ((v.u >> 16) & 1u);
  return (unsigned short)(r >> 16);
}

// async global->LDS, 16B per lane; LDS dest = wave-uniform base + lane*16
__device__ __forceinline__ void gload16(const unsigned short* g, unsigned short* l) {
  __builtin_amdgcn_global_load_lds(
      (const __attribute__((address_space(1))) unsigned int*)g,
      (__attribute__((address_space(3))) unsigned int*)l, 16, 0, 0);
}

// ---------------- prep: concat+pos transpose, all weight cvts, vsum zero ----------------
__global__ __launch_bounds__(256) void prep_k(const float* __restrict__ x,
                                              const float* __restrict__ Wq,
                                              const float* __restrict__ Wk,
                                              const float* __restrict__ Wv,
                                              const float* __restrict__ Wc,
                                              const float* __restrict__ Wres,
                                              const float* __restrict__ W1,
                                              const float* __restrict__ W2,
                                              unsigned short* __restrict__ xpt,
                                              unsigned short* __restrict__ wqb,
                                              unsigned short* __restrict__ wkb,
                                              unsigned short* __restrict__ wvb,
                                              unsigned short* __restrict__ wcb,
                                              unsigned short* __restrict__ wresb,
                                              unsigned short* __restrict__ w1b,
                                              unsigned short* __restrict__ w2b,
                                              float* __restrict__ vsum) {
  __shared__ float tile[64][65];
  int blk = blockIdx.x;
  int t = threadIdx.x;
  if (blk < 512) {
    int b = blk >> 8, c0 = ((blk >> 5) & 7) * 64, l0 = (blk & 31) * 64;
    if (c0 < NIND) {
      const float* src = x + ((size_t)b * NIND + c0) * SEQLEN;
      int ll = t & 63, cq = t >> 6;
#pragma unroll
      for (int i = 0; i < 16; ++i) {
        int cl = cq * 16 + i;
        tile[cl][ll] = src[(size_t)cl * SEQLEN + l0 + ll];
      }
      __syncthreads();
      int cl2 = t & 63, lq = t >> 6;
      unsigned short* dst = xpt + ((size_t)b * SEQLEN + l0) * NCIN + c0;
#pragma unroll
      for (int i = 0; i < 16; ++i) {
        int l = lq * 16 + i;
        dst[(size_t)l * NCIN + cl2] = f2bf(tile[cl2][l]);
      }
    } else {
      if (b == 1) return;              // pos is batch-independent; b==0 block writes both
      int c = c0 + (t & 63);
      int j = c - NIND;
      int i = (j < NPOS / 2) ? j : j - NPOS / 2;
      const double base = (double)1.2f;
      double p = 1.0;
      for (int tt = 0; tt <= i; ++tt) p *= base;
      float w = 0.8f + (float)p;
      float swl = (float)SEQLEN / w;
      const float two_pi = (float)(2.0 * 3.14159265358979323846);
      int wv = t >> 6;
      unsigned short* dst0 = xpt;
      unsigned short* dst1 = xpt + (size_t)SEQLEN * NCIN;
#pragma unroll
      for (int it = 0; it < 16; ++it) {
        int l = l0 + 16 * wv + it;
        float arg = (two_pi * (float)l) / swl;
        unsigned short val = f2bf((j < NPOS / 2) ? sinf(arg) : cosf(arg));
        dst0[(size_t)l * NCIN + c] = val;
        dst1[(size_t)l * NCIN + c] = val;
      }
    }
  } else if (blk == 1360) {
    ((float4*)vsum)[t] = make_float4(0.f, 0.f, 0.f, 0.f);
  } else {
    const float* in;
    unsigned short* out;
    int idx4;
    if (blk < 1280) {
      int i = (blk - 512) * 256 + t;
      int which = i >> 16;
      idx4 = i & 65535;
      in = (which == 0) ? Wq : ((which == 1) ? Wk : Wv);
      out = (which == 0) ? wqb : ((which == 1) ? wkb : wvb);
    } else if (blk < 1312) { in = Wc;   out = wcb;   idx4 = (blk - 1280) * 256 + t; }
    else if (blk < 1328)   { in = Wres; out = wresb; idx4 = (blk - 1312) * 256 + t; }
    else if (blk < 1344)   { in = W1;   out = w1b;   idx4 = (blk - 1328) * 256 + t; }
    else                   { in = W2;   out = w2b;   idx4 = (blk - 1344) * 256 + t; }
    float4 v = ((const float4*)in)[idx4];
    ((ushort4*)out)[idx4] = make_ushort4(f2bf(v.x), f2bf(v.y), f2bf(v.z), f2bf(v.w));
  }
}

// ---------------- fused QKV MFMA GEMM: 64x128, BK=64, 2-deep counted-vmcnt pipeline ----------------
__global__ __launch_bounds__(256) void qkv_gemm_k(const unsigned short* __restrict__ Wqb,
                                                  const unsigned short* __restrict__ Wkb,
                                                  const unsigned short* __restrict__ Wvb,
                                                  const unsigned short* __restrict__ xpt,
                                                  unsigned short* __restrict__ qt,
                                                  unsigned short* __restrict__ kt,
                                                  unsigned short* __restrict__ vb,
                                                  float* __restrict__ vsum) {
  __shared__ alignas(16) unsigned short lds[24576];   // 2 x (A 64x64 | B 128x64)

  int bz = blockIdx.z;
  int y = blockIdx.y;
  int ysel = y >> 3;
  int m0 = (y & 7) * 64;
  int n0 = blockIdx.x * 128;
  const unsigned short* W = (ysel == 0) ? Wqb : ((ysel == 1) ? Wkb : Wvb);
  const unsigned short* Bg = xpt + (size_t)bz * SEQLEN * NCIN;

  int t = threadIdx.x;
  int w = t >> 6, lane = t & 63, lr = lane & 15, hi = lane >> 4;
  int wm = w >> 1, wn = w & 1;

  int sr = lane >> 3;
  int scs = ((lane & 7) ^ sr) * 8;   // shorts, source pre-swizzled by row
  const unsigned short* gA0 = W  + (size_t)(m0 + 16 * w + sr) * 512 + scs;
  const unsigned short* gB0 = Bg + (size_t)(n0 + 32 * w + sr) * 512 + scs;

  int swz = (lr & 7) << 3;           // read-side XOR (shorts)

  f32x4 acc[2][4];
#pragma unroll
  for (int i = 0; i < 2; ++i)
#pragma unroll
    for (int j = 0; j < 4; ++j) acc[i][j] = (f32x4){0.f, 0.f, 0.f, 0.f};

  auto stage = [&](int buf, int k0) {
    unsigned short* Ad = lds + buf * 12288 + (16 * w) * 64;
    unsigned short* Bd = lds + buf * 12288 + 4096 + (32 * w) * 64;
    gload16(gA0 + k0,            Ad);
    gload16(gA0 + k0 + 8 * 512,  Ad + 8 * 64);
    gload16(gB0 + k0,            Bd);
    gload16(gB0 + k0 + 8 * 512,  Bd + 8 * 64);
    gload16(gB0 + k0 + 16 * 512, Bd + 16 * 64);
    gload16(gB0 + k0 + 24 * 512, Bd + 24 * 64);
  };
  auto compute = [&](int buf) {
    const unsigned short* Ar = lds + buf * 12288;
    const unsigned short* Br = Ar + 4096;
#pragma unroll
    for (int ks = 0; ks < 2; ++ks) {
      s16x8 af[2], bfv[4];
#pragma unroll
      for (int mt = 0; mt < 2; ++mt)
        af[mt] = *(const s16x8*)&Ar[(32 * wm + 16 * mt + lr) * 64 + ((32 * ks + 8 * hi) ^ swz)];
#pragma unroll
      for (int nt = 0; nt < 4; ++nt)
        bfv[nt] = *(const s16x8*)&Br[(64 * wn + 16 * nt + lr) * 64 + ((32 * ks + 8 * hi) ^ swz)];
#pragma unroll
      for (int mt = 0; mt < 2; ++mt)
#pragma unroll
        for (int nt = 0; nt < 4; ++nt)
          acc[mt][nt] = __builtin_amdgcn_mfma_f32_16x16x32_bf16(af[mt], bfv[nt], acc[mt][nt], 0, 0, 0);
    }
  };

  stage(0, 0);
  stage(1, 64);
#pragma unroll
  for (int it = 0; it < 8; ++it) {
    if (it < 7) {
      asm volatile("s_waitcnt vmcnt(6)" ::: "memory");
    } else {
      asm volatile("s_waitcnt vmcnt(0)" ::: "memory");
    }
    __builtin_amdgcn_s_barrier();
    compute(it & 1);
    __builtin_amdgcn_s_barrier();
    if (it < 6) stage(it & 1, (it + 2) * 64);
  }
  __syncthreads();

  if (ysel == 2) {
#pragma unroll
    for (int mt = 0; mt < 2; ++mt)
#pragma unroll
      for (int reg = 0; reg < 4; ++reg) {
        float p = acc[mt][0][reg] + acc[mt][1][reg] + acc[mt][2][reg] + acc[mt][3][reg];
        p += __shfl_xor(p, 1, 64);
        p += __shfl_xor(p, 2, 64);
        p += __shfl_xor(p, 4, 64);
        p += __shfl_xor(p, 8, 64);
        if (lr == 0)
          atomicAdd(&vsum[bz * 512 + m0 + 32 * wm + 16 * mt + 4 * hi + reg], p);
      }
  }

  if (ysel < 2) {
    unsigned short* Cl = lds;
#pragma unroll
    for (int mt = 0; mt < 2; ++mt)
#pragma unroll
      for (int nt = 0; nt < 4; ++nt) {
        int lloc = 64 * wn + 16 * nt + lr;
        int d0 = 32 * wm + 16 * mt + 4 * hi;
        *(ushort4*)&Cl[lloc * 68 + d0] = make_ushort4(f2bf(acc[mt][nt][0]), f2bf(acc[mt][nt][1]),
                                                      f2bf(acc[mt][nt][2]), f2bf(acc[mt][nt][3]));
      }
    __syncthreads();
    int h = m0 >> 6;
    unsigned short* Cb = ((ysel == 0) ? qt : kt) + ((size_t)(bz * NH + h) * SEQLEN + n0) * 64;
    int rr = t >> 1, cc = (t & 1) * 32;
#pragma unroll
    for (int j = 0; j < 4; ++j)
      *(int4*)&Cb[(size_t)rr * 64 + cc + 8 * j] = *(const int4*)&Cl[rr * 68 + cc + 8 * j];
  } else {
    unsigned short* Cl2 = lds;
#pragma unroll
    for (int mt = 0; mt < 2; ++mt)
#pragma unroll
      for (int nt = 0; nt < 4; ++nt) {
        int lloc = 64 * wn + 16 * nt + lr;
#pragma unroll
        for (int reg = 0; reg < 4; ++reg)
          Cl2[(32 * wm + 16 * mt + 4 * hi + reg) * 132 + lloc] = f2bf(acc[mt][nt][reg]);
      }
    __syncthreads();
    int dd = t >> 2, cc = (t & 3) * 32;
    unsigned short* Vb = vb + ((size_t)(bz * 512 + m0 + dd)) * SEQLEN + n0;
#pragma unroll
    for (int j = 0; j < 4; ++j)
      *(int4*)&Vb[cc + 8 * j] = *(const int4*)&Cl2[dd * 132 + cc + 8 * j];
  }
}

// ---------------- banded attention: WAVE-PER-BLOCK (64 thr), 16 rows, 144-window ----------------
__global__ __launch_bounds__(64) void attn_k(const unsigned short* __restrict__ qt,
                                             const unsigned short* __restrict__ kt,
                                             const unsigned short* __restrict__ vb,
                                             const float* __restrict__ vsum,
                                             unsigned short* __restrict__ attnt) {
  __shared__ alignas(16) unsigned short Ps[16][168];   // 16 rows x 168 (cols 144..167 zero)
  __shared__ float rowcoef[16];

  int bz = blockIdx.z, hh = blockIdx.y;
  int l0 = blockIdx.x * 16;
  int bh = bz * NH + hh;
  const unsigned short* Qb = qt + (size_t)bh * SEQLEN * 64;
  const unsigned short* Kb = kt + (size_t)bh * SEQLEN * 64;
  const unsigned short* Vp = vb + (size_t)(bz * 512 + hh * 64) * SEQLEN;
  int vsbase = bz * 512 + hh * 64;

  int t = threadIdx.x;                 // one wave
  int lr = t & 15, hi = t >> 4;

  s16x8 a0 = *(const s16x8*)(Qb + ((size_t)(l0 + lr)) * 64 + 8 * hi);
  s16x8 a1 = *(const s16x8*)(Qb + ((size_t)(l0 + lr)) * 64 + 32 + 8 * hi);

  f32x4 sc[9];
#pragma unroll
  for (int ct = 0; ct < 9; ++ct) {
    int m = l0 - 64 + 16 * ct + lr;
    const unsigned short* kp = Kb + (ptrdiff_t)m * 64;
    s16x8 b0 = *(const s16x8*)(kp + 8 * hi);
    s16x8 b1 = *(const s16x8*)(kp + 32 + 8 * hi);
    f32x4 acc = {0.f, 0.f, 0.f, 0.f};
    acc = __builtin_amdgcn_mfma_f32_16x16x32_bf16(a0, b0, acc, 0, 0, 0);
    acc = __builtin_amdgcn_mfma_f32_16x16x32_bf16(a1, b1, acc, 0, 0, 0);
    sc[ct] = acc;
  }

  float rcv[4];
#pragma unroll
  for (int i = 0; i < 4; ++i) {
    int r = 4 * hi + i;
    int l = l0 + r;
    float mx = 0.0f;
    float sv[9];
#pragma unroll
    for (int ct = 0; ct < 9; ++ct) {
      int c = 16 * ct + lr;
      int m = l0 - 64 + c;
      bool ib = (c >= r) && (c <= r + 128) && (m >= 0) && (m < SEQLEN);
      float s = sc[ct][i] * 0.125f;
      sv[ct] = ib ? s : -1e30f;
      mx = ib ? fmaxf(mx, s) : mx;
    }
    mx = fmaxf(mx, __shfl_xor(mx, 1, 64));
    mx = fmaxf(mx, __shfl_xor(mx, 2, 64));
    mx = fmaxf(mx, __shfl_xor(mx, 4, 64));
    mx = fmaxf(mx, __shfl_xor(mx, 8, 64));
    float e0 = expf(-mx);
    float zs = 0.f;
#pragma unroll
    for (int ct = 0; ct < 9; ++ct) {
      float e = (sv[ct] > -1e29f) ? expf(sv[ct] - mx) : 0.0f;
      sv[ct] = e;
      zs += e;
    }
    zs += __shfl_xor(zs, 1, 64);
    zs += __shfl_xor(zs, 2, 64);
    zs += __shfl_xor(zs, 4, 64);
    zs += __shfl_xor(zs, 8, 64);
    int lo = l - NREC; if (lo < 0) lo = 0;
    int hi2 = l + NREC; if (hi2 > SEQLEN - 1) hi2 = SEQLEN - 1;
    float inv = 1.0f / (zs + (float)(SEQLEN - (hi2 - lo + 1)) * e0);
    rcv[i] = e0 * inv;
#pragma unroll
    for (int ct = 0; ct < 9; ++ct)
      sc[ct][i] = (sv[ct] > 0.0f) ? (sv[ct] - e0) * inv : 0.0f;
  }

#pragma unroll
  for (int i = 0; i < 4; ++i) {
    int r = 4 * hi + i;
#pragma unroll
    for (int ct = 0; ct < 9; ++ct)
      Ps[r][16 * ct + lr] = f2bf(sc[ct][i]);
  }
  for (int z = t; z < 16 * 24; z += 64) Ps[z / 24][144 + z % 24] = 0;
  if (lr == 0) {
#pragma unroll
    for (int i = 0; i < 4; ++i) rowcoef[4 * hi + i] = rcv[i];
  }
  __syncthreads();

  float rcf = rowcoef[lr];
  unsigned short* Ob = attnt + ((size_t)bz * SEQLEN + l0 + lr) * 512 + hh * 64;
#pragma unroll
  for (int vt = 0; vt < 4; ++vt) {
    f32x4 acc = {0.f, 0.f, 0.f, 0.f};
#pragma unroll
    for (int ks = 0; ks < 5; ++ks) {
      int m8 = l0 - 64 + 32 * ks + 8 * hi;
      s16x8 av = *(const s16x8*)(Vp + (ptrdiff_t)(16 * vt + lr) * SEQLEN + m8);
      s16x8 b = *(const s16x8*)&Ps[lr][32 * ks + 8 * hi];
      acc = __builtin_amdgcn_mfma_f32_16x16x32_bf16(av, b, acc, 0, 0, 0);
    }
    float vsv[4];
#pragma unroll
    for (int reg = 0; reg < 4; ++reg) vsv[reg] = vsum[vsbase + 16 * vt + 4 * hi + reg];
    ushort4 o = make_ushort4(f2bf(acc[0] + rcf * vsv[0]), f2bf(acc[1] + rcf * vsv[1]),
                             f2bf(acc[2] + rcf * vsv[2]), f2bf(acc[3] + rcf * vsv[3]));
    *(ushort4*)&Ob[16 * vt + 4 * hi] = o;
  }
}

// ---------------- fused tail, wave-per-block (64 threads, 16 l-cols each) ----------------
__global__ __launch_bounds__(64) void tail_k(const unsigned short* __restrict__ wcb,
                                             const unsigned short* __restrict__ wresb,
                                             const unsigned short* __restrict__ w1b,
                                             const unsigned short* __restrict__ w2b,
                                             const unsigned short* __restrict__ attnt,
                                             const unsigned short* __restrict__ xpt,
                                             const float* __restrict__ g1v,
                                             const float* __restrict__ b1v,
                                             const float* __restrict__ g2v,
                                             const float* __restrict__ b2v,
                                             float* __restrict__ outp) {
  __shared__ float gs1[64], bs1[64], gs2[64], bs2[64];
  __shared__ alignas(16) unsigned short pw[16][72];
  __shared__ alignas(16) unsigned short hw[16][264];

  int b = blockIdx.y;
  int l0 = blockIdx.x * 16;
  int t = threadIdx.x;                 // 0..63, one wave
  int lr = t & 15, hi = t >> 4;
  gs1[t] = g1v[t]; bs1[t] = b1v[t]; gs2[t] = g2v[t]; bs2[t] = b2v[t];
  __syncthreads();

  int lloc = lr;
  const unsigned short* brow = attnt + ((size_t)b * SEQLEN + l0 + lloc) * 512;
  const unsigned short* xrow = xpt + ((size_t)b * SEQLEN + l0 + lloc) * 512;

  // ---- phase 1: pred = LN1(Wc @ attnt + Wres @ x) ----
  f32x4 acc[4];
#pragma unroll
  for (int i = 0; i < 4; ++i) acc[i] = (f32x4){0.f, 0.f, 0.f, 0.f};
#pragma unroll
  for (int ks = 0; ks < 16; ++ks) {
    s16x8 bf = *(const s16x8*)(brow + 32 * ks + 8 * hi);
#pragma unroll
    for (int mt = 0; mt < 4; ++mt) {
      s16x8 af = *(const s16x8*)(wcb + (size_t)(16 * mt + lr) * 512 + 32 * ks + 8 * hi);
      acc[mt] = __builtin_amdgcn_mfma_f32_16x16x32_bf16(af, bf, acc[mt], 0, 0, 0);
    }
  }
#pragma unroll
  for (int ks = 0; ks < 8; ++ks) {
    s16x8 bf = *(const s16x8*)(xrow + 32 * ks + 8 * hi);
#pragma unroll
    for (int mt = 0; mt < 4; ++mt) {
      s16x8 af = *(const s16x8*)(wresb + (size_t)(16 * mt + lr) * 256 + 32 * ks + 8 * hi);
      acc[mt] = __builtin_amdgcn_mfma_f32_16x16x32_bf16(af, bf, acc[mt], 0, 0, 0);
    }
  }
  float resid[4][4];
  {
    float sum = 0.f, sq = 0.f;
#pragma unroll
    for (int mt = 0; mt < 4; ++mt)
#pragma unroll
      for (int reg = 0; reg < 4; ++reg) { float v = acc[mt][reg]; sum += v; sq += v * v; }
    sum += __shfl_xor(sum, 16, 64); sq += __shfl_xor(sq, 16, 64);
    sum += __shfl_xor(sum, 32, 64); sq += __shfl_xor(sq, 32, 64);
    float mu = sum * (1.0f / 64.0f);
    float var = sq * (1.0f / 64.0f) - mu * mu;
    float rstd = rsqrtf(var + 1e-5f);
#pragma unroll
    for (int mt = 0; mt < 4; ++mt) {
      float o[4];
#pragma unroll
      for (int reg = 0; reg < 4; ++reg) {
        int m = 16 * mt + 4 * hi + reg;
        o[reg] = (acc[mt][reg] - mu) * rstd * gs1[m] + bs1[m];
        resid[mt][reg] = o[reg];
      }
      *(ushort4*)&pw[lr][16 * mt + 4 * hi] =
          make_ushort4(f2bf(o[0]), f2bf(o[1]), f2bf(o[2]), f2bf(o[3]));
    }
  }
  __syncthreads();

  // ---- phase 2: h = gelu(W1 @ pred) ----
  {
    s16x8 bf0 = *(const s16x8*)&pw[lr][8 * hi];
    s16x8 bf1 = *(const s16x8*)&pw[lr][32 + 8 * hi];
#pragma unroll
    for (int mt = 0; mt < 16; ++mt) {
      s16x8 a0 = *(const s16x8*)(w1b + (size_t)(16 * mt + lr) * 64 + 8 * hi);
      s16x8 a1 = *(const s16x8*)(w1b + (size_t)(16 * mt + lr) * 64 + 32 + 8 * hi);
      f32x4 a2 = {0.f, 0.f, 0.f, 0.f};
      a2 = __builtin_amdgcn_mfma_f32_16x16x32_bf16(a0, bf0, a2, 0, 0, 0);
      a2 = __builtin_amdgcn_mfma_f32_16x16x32_bf16(a1, bf1, a2, 0, 0, 0);
      float v0 = a2[0], v1 = a2[1], v2 = a2[2], v3 = a2[3];
      v0 = 0.5f * v0 * (1.0f + erff(v0 * 0.70710678118654752440f));
      v1 = 0.5f * v1 * (1.0f + erff(v1 * 0.70710678118654752440f));
      v2 = 0.5f * v2 * (1.0f + erff(v2 * 0.70710678118654752440f));
      v3 = 0.5f * v3 * (1.0f + erff(v3 * 0.70710678118654752440f));
      *(ushort4*)&hw[lr][16 * mt + 4 * hi] = make_ushort4(f2bf(v0), f2bf(v1), f2bf(v2), f2bf(v3));
    }
  }
  __syncthreads();

  // ---- phase 3: out = LN2(W2 @ h + pred) ----
  f32x4 acc3[4];
#pragma unroll
  for (int i = 0; i < 4; ++i) acc3[i] = (f32x4){0.f, 0.f, 0.f, 0.f};
#pragma unroll
  for (int ks = 0; ks < 8; ++ks) {
    s16x8 bf = *(const s16x8*)&hw[lr][32 * ks + 8 * hi];
#pragma unroll
    for (int mt = 0; mt < 4; ++mt) {
      s16x8 af = *(const s16x8*)(w2b + (size_t)(16 * mt + lr) * 256 + 32 * ks + 8 * hi);
      acc3[mt] = __builtin_amdgcn_mfma_f32_16x16x32_bf16(af, bf, acc3[mt], 0, 0, 0);
    }
  }
#pragma unroll
  for (int mt = 0; mt < 4; ++mt)
#pragma unroll
    for (int reg = 0; reg < 4; ++reg) acc3[mt][reg] += resid[mt][reg];
  float sum = 0.f, sq = 0.f;
#pragma unroll
  for (int mt = 0; mt < 4; ++mt)
#pragma unroll
    for (int reg = 0; reg < 4; ++reg) { float v = acc3[mt][reg]; sum += v; sq += v * v; }
  sum += __shfl_xor(sum, 16, 64); sq += __shfl_xor(sq, 16, 64);
  sum += __shfl_xor(sum, 32, 64); sq += __shfl_xor(sq, 32, 64);
  float mu = sum * (1.0f / 64.0f);
  float var = sq * (1.0f / 64.0f) - mu * mu;
  float rstd = rsqrtf(var + 1e-5f);
  float* ob = outp + (size_t)b * 64 * SEQLEN;
  int l = l0 + lloc;
#pragma unroll
  for (int mt = 0; mt < 4; ++mt)
#pragma unroll
    for (int reg = 0; reg < 4; ++reg) {
      int m = 16 * mt + 4 * hi + reg;
      ob[(size_t)m * SEQLEN + l] = (acc3[mt][reg] - mu) * rstd * gs2[m] + bs2[m];
    }
}

extern "C" void kernel_launch(void* const* d_in, const int* in_sizes, int n_in,
                              void* d_out, int out_size, void* d_ws, size_t ws_size,
                              hipStream_t stream) {
  const float* x    = (const float*)d_in[0];
  const float* Wq   = (const float*)d_in[1];
  const float* Wk   = (const float*)d_in[2];
  const float* Wv   = (const float*)d_in[3];
  const float* Wres = (const float*)d_in[4];
  const float* Wc   = (const float*)d_in[5];
  const float* ln1g = (const float*)d_in[6];
  const float* ln1b = (const float*)d_in[7];
  const float* W1   = (const float*)d_in[8];
  const float* W2   = (const float*)d_in[9];
  const float* ln2g = (const float*)d_in[10];
  const float* ln2b = (const float*)d_in[11];

  char* base = (char*)d_ws;
  unsigned short* xpt   = (unsigned short*)base; base += (size_t)2097152 * 2;
  unsigned short* wqb   = (unsigned short*)base; base += (size_t)262144 * 2;
  unsigned short* wkb   = (unsigned short*)base; base += (size_t)262144 * 2;
  unsigned short* wvb   = (unsigned short*)base; base += (size_t)262144 * 2;
  unsigned short* wcb   = (unsigned short*)base; base += (size_t)32768 * 2;
  unsigned short* wresb = (unsigned short*)base; base += (size_t)16384 * 2;
  unsigned short* w1b   = (unsigned short*)base; base += (size_t)16384 * 2;
  unsigned short* w2b   = (unsigned short*)base; base += (size_t)16384 * 2;
  unsigned short* qt    = (unsigned short*)base; base += (size_t)2097152 * 2;
  unsigned short* kt    = (unsigned short*)base; base += (size_t)2097152 * 2;
  unsigned short* vbb   = (unsigned short*)base; base += (size_t)2097152 * 2;
  float* vsum           = (float*)base;          base += (size_t)1024 * 4;
  unsigned short* attnt = (unsigned short*)base; base += (size_t)2097152 * 2;
  float* outp = (float*)d_out;

  prep_k<<<1361, 256, 0, stream>>>(x, Wq, Wk, Wv, Wc, Wres, W1, W2,
                                   xpt, wqb, wkb, wvb, wcb, wresb, w1b, w2b, vsum);
  qkv_gemm_k<<<dim3(16, 24, NBATCH), 256, 0, stream>>>(wqb, wkb, wvb, xpt, qt, kt, vbb, vsum);
  attn_k<<<dim3(128, NH, NBATCH), 64, 0, stream>>>(qt, kt, vbb, vsum, attnt);
  tail_k<<<dim3(128, NBATCH), 64, 0, stream>>>(wcb, wresb, w1b, w2b, attnt, xpt,
                                               ln1g, ln1b, ln2g, ln2b, outp);
}